// Round 19
// baseline (110.647 us; speedup 1.0000x reference)
//
#include <hip/hip_runtime.h>
#include <cstdint>
#include <cstddef>

// Problem constants: B=64, R=36, W=32, D=1024
// Ab = [s;x] bf16 : 4096 x 1024 (rows 0..2047 = s words, 2048..4095 = x words)
// Bb = im bf16    : 2304 x 1024
// dot bf16        : 4096 x 2304

typedef __attribute__((ext_vector_type(8))) short short8;
typedef __attribute__((ext_vector_type(4))) float f32x4;
typedef __attribute__((ext_vector_type(2))) float f2;   // -> v_pk_* f32 ops

__device__ __forceinline__ unsigned short f2bf(float f) {
  unsigned u = __float_as_uint(f);
  u += 0x7FFFu + ((u >> 16) & 1u);
  return (unsigned short)(u >> 16);
}
__device__ __forceinline__ float rcpf(float x) { return __builtin_amdgcn_rcpf(x); }

// ---------------- K1: fused gram (blocks 0..2303) + prep (blocks 2304..8703) ----------------
__global__ __launch_bounds__(256) void k_prep(const float* __restrict__ s,
                                              const float* __restrict__ x,
                                              const float* __restrict__ im,
                                              unsigned short* __restrict__ Ab,
                                              unsigned short* __restrict__ Bb,
                                              float* __restrict__ w1,
                                              float* __restrict__ xn_r,
                                              float* __restrict__ imn_r,
                                              float* __restrict__ G) {
  int blk = blockIdx.x;
  if (blk < 2304) {
    // ---- gram: G[b] row r = im[b,r,:] @ im[b,:,:]^T (fp32, proven) ----
    int b = blk / 36, r = blk - b * 36;
    int wid = threadIdx.x >> 6, l = threadIdx.x & 63;
    const float* rowr = im + ((size_t)b*36 + r) * 1024;
    float4 my[4];
    #pragma unroll
    for (int j = 0; j < 4; ++j) my[j] = ((const float4*)rowr)[j*64 + l];
    float* Gr = G + ((size_t)b*36 + r) * 36;
    for (int rp = wid; rp < 36; rp += 4) {
      const float* rowp = im + ((size_t)b*36 + rp) * 1024;
      float p = 0.f;
      #pragma unroll
      for (int j = 0; j < 4; ++j) {
        float4 u = ((const float4*)rowp)[j*64 + l];
        p += my[j].x*u.x + my[j].y*u.y + my[j].z*u.z + my[j].w*u.w;
      }
      #pragma unroll
      for (int o = 32; o > 0; o >>= 1) p += __shfl_down(p, o, 64);
      if (l == 0) Gr[rp] = p;
    }
    return;
  }
  // ---- prep: fp32 -> bf16 + norms ----
  int row = blk - 2304, tid = threadIdx.x;
  const float* src; unsigned short* dst; float* np; int recip;
  if (row < 2048)      { src = s  + (size_t)row * 1024;          dst = Ab + (size_t)row * 1024;          np = w1    + row;          recip = 0; }
  else if (row < 4096) { src = x  + (size_t)(row - 2048) * 1024; dst = Ab + (size_t)row * 1024;          np = xn_r  + (row - 2048); recip = 1; }
  else                 { src = im + (size_t)(row - 4096) * 1024; dst = Bb + (size_t)(row - 4096) * 1024; np = imn_r + (row - 4096); recip = 1; }
  float4 f = ((const float4*)src)[tid];
  ushort4 h;
  h.x = f2bf(f.x); h.y = f2bf(f.y); h.z = f2bf(f.z); h.w = f2bf(f.w);
  ((ushort4*)dst)[tid] = h;
  float p = f.x*f.x + f.y*f.y + f.z*f.z + f.w*f.w;
  #pragma unroll
  for (int o = 32; o > 0; o >>= 1) p += __shfl_down(p, o, 64);
  __shared__ float red[4];
  if ((tid & 63) == 0) red[tid >> 6] = p;
  __syncthreads();
  if (tid == 0) {
    float n = sqrtf(red[0] + red[1] + red[2] + red[3]);
    *np = recip ? 1.f / (n + 1e-12f) : n;
  }
}

// ---------------- K2: bf16 MFMA GEMM, 128x96 tile (grid 24x32 = 768 = 3/CU exact) ----------------
__global__ __launch_bounds__(256) void k_gemm_mfma(const unsigned short* __restrict__ A,
                                                   const unsigned short* __restrict__ B,
                                                   unsigned short* __restrict__ dot) {
  __shared__ unsigned short lA[128 * 32];
  __shared__ unsigned short lB[96 * 32];
  int tid = threadIdx.x;
  int bn = blockIdx.x * 96, bm = blockIdx.y * 128;
  int wid = tid >> 6, l = tid & 63;
  int wr = (wid >> 1) * 64, wc = (wid & 1) * 48;
  int lr = l & 15, lq = l >> 4;

  f32x4 acc[4][3] = {};

  int row_a = tid >> 2;
  int kq = (tid & 3) * 8;
  const unsigned short* gA = A + (size_t)(bm + row_a) * 1024 + kq;
  const unsigned short* gB = B + (size_t)(bn + row_a) * 1024 + kq;    // rows 0..63
  unsigned loff = (unsigned)tid * 16u;

  for (int kt = 0; kt < 1024; kt += 32) {
    __builtin_amdgcn_global_load_lds(
        (const __attribute__((address_space(1))) void*)(gA + kt),
        (__attribute__((address_space(3))) void*)((char*)lA + loff), 16, 0, 0);
    __builtin_amdgcn_global_load_lds(
        (const __attribute__((address_space(1))) void*)(gA + 64*1024 + kt),
        (__attribute__((address_space(3))) void*)((char*)lA + 4096 + loff), 16, 0, 0);
    __builtin_amdgcn_global_load_lds(
        (const __attribute__((address_space(1))) void*)(gB + kt),
        (__attribute__((address_space(3))) void*)((char*)lB + loff), 16, 0, 0);
    if (tid < 128)                                                     // rows 64..95
      __builtin_amdgcn_global_load_lds(
          (const __attribute__((address_space(1))) void*)(gB + 64*1024 + kt),
          (__attribute__((address_space(3))) void*)((char*)lB + 4096 + loff), 16, 0, 0);
    __syncthreads();

    short8 af[4], bfr[3];
    #pragma unroll
    for (int mi = 0; mi < 4; ++mi)
      af[mi] = *(const short8*)&lA[(wr + mi*16 + lr) * 32 + lq * 8];
    #pragma unroll
    for (int ni = 0; ni < 3; ++ni)
      bfr[ni] = *(const short8*)&lB[(wc + ni*16 + lr) * 32 + lq * 8];
    #pragma unroll
    for (int mi = 0; mi < 4; ++mi)
      #pragma unroll
      for (int ni = 0; ni < 3; ++ni)
        acc[mi][ni] = __builtin_amdgcn_mfma_f32_16x16x32_bf16(af[mi], bfr[ni], acc[mi][ni], 0, 0, 0);
    __syncthreads();
  }

  // C/D layout: col = lane&15, row = (lane>>4)*4 + reg
  #pragma unroll
  for (int mi = 0; mi < 4; ++mi)
    #pragma unroll
    for (int ni = 0; ni < 3; ++ni) {
      int gcol = bn + wc + ni*16 + lr;
      #pragma unroll
      for (int q = 0; q < 4; ++q) {
        int grow = bm + wr + mi*16 + lq*4 + q;
        dot[(size_t)grow * 2304 + gcol] = f2bf(acc[mi][ni][q]);
      }
    }
}

// ---------------- wave reduction helpers ----------------
template<int C>
__device__ __forceinline__ float dpp_add(float v) {
  return v + __int_as_float(__builtin_amdgcn_mov_dpp(__float_as_int(v), C, 0xF, 0xF, true));
}
template<int C>
__device__ __forceinline__ float dpp_max(float v) {
  return fmaxf(v, __int_as_float(__builtin_amdgcn_mov_dpp(__float_as_int(v), C, 0xF, 0xF, true)));
}
__device__ __forceinline__ float bsum32(float v) {   // sum over lane bits 0..4
  v = dpp_add<0xB1>(v);    // xor1
  v = dpp_add<0x4E>(v);    // xor2
  v = dpp_add<0x141>(v);   // half mirror (xor4-equiv)
  v = dpp_add<0x128>(v);   // row_ror:8 (xor8-equiv)
  v += __shfl_xor(v, 16, 64);
  return v;
}
__device__ __forceinline__ float bsum16(float v) {   // sum over lane bits 0..3 (one DPP row), all-VALU
  v = dpp_add<0xB1>(v);
  v = dpp_add<0x4E>(v);
  v = dpp_add<0x141>(v);
  v = dpp_add<0x128>(v);
  return v;
}
__device__ __forceinline__ float bmax32(float v) {
  v = dpp_max<0xB1>(v);
  v = dpp_max<0x4E>(v);
  v = dpp_max<0x141>(v);
  v = dpp_max<0x128>(v);
  v = fmaxf(v, __shfl_xor(v, 16, 64));
  return v;
}

// ---------------- K3: wave-role split — even waves = score, odd = IPOT (rq/w16 layout) ----------------
__global__ __launch_bounds__(256, 4) void k_pair2(const unsigned short* __restrict__ dotb,
                                                  const float* __restrict__ Gm,
                                                  const float* __restrict__ w1m,
                                                  const float* __restrict__ xnrm,
                                                  const float* __restrict__ imnrm,
                                                  float* __restrict__ S,
                                                  float* __restrict__ Sot) {
  int wid  = threadIdx.x >> 6;
  int g    = blockIdx.x * 4 + wid;           // 0..8191
  int pair = g >> 1;                         // 0..4095
  int role = g & 1;                          // 0 = score, 1 = ipot
  int c = pair >> 6, i = pair & 63;
  int l = threadIdx.x & 63;

  if (role == 0) {
    // ================= SCORE path (h = l>>5, w = l&31) =================
    int h = l >> 5, w = l & 31;
    int r0 = h * 18;
    const unsigned* drow = (const unsigned*)(dotb + (size_t)(c*32 + w) * 2304 + i*36 + r0);
    float w1 = w1m[c*32 + w];

    f2 d2[9];
    #pragma unroll
    for (int k = 0; k < 9; ++k) {
      unsigned u = drow[k];
      d2[k][0] = __uint_as_float(u << 16);
      d2[k][1] = __uint_as_float(u & 0xFFFF0000u);
    }

    f2 p2[9];
    #pragma unroll
    for (int k = 0; k < 9; ++k) {
      f2 t = d2[k] * 0.1f;
      f2 fv;
      fv[0] = fmaxf(d2[k][0], t[0]);
      fv[1] = fmaxf(d2[k][1], t[1]);
      f2 sq = fv * fv;
      float t0 = bsum32(sq[0]);
      float t1 = bsum32(sq[1]);
      f2 rs;   // 9/sqrt(t) = rsqrt(t/81)
      rs[0] = __builtin_amdgcn_rsqf(fmaxf(t0 * 0.012345679f, 1e-30f));
      rs[1] = __builtin_amdgcn_rsqf(fmaxf(t1 * 0.012345679f, 1e-30f));
      p2[k] = fv * rs;
    }
    float mx = fmaxf(fmaxf(p2[0][0], p2[0][1]), fmaxf(p2[1][0], p2[1][1]));
    #pragma unroll
    for (int k = 2; k < 9; ++k) mx = fmaxf(mx, fmaxf(p2[k][0], p2[k][1]));
    mx = fmaxf(mx, __shfl_xor(mx, 32, 64));        // max over all 36 r

    f2 e2[9];
    f2 sum2 = {0.f, 0.f}, nu2 = {0.f, 0.f};
    #pragma unroll
    for (int k = 0; k < 9; ++k) {
      e2[k][0] = __expf(p2[k][0] - mx);
      e2[k][1] = __expf(p2[k][1] - mx);
      sum2 += e2[k];
      nu2 += e2[k] * d2[k];
    }
    float sum = sum2[0] + sum2[1];
    float numu = nu2[0] + nu2[1];
    sum  += __shfl_xor(sum, 32, 64);
    numu += __shfl_xor(numu, 32, 64);
    float inv = rcpf(sum);
    float num = numu * inv;

    f2 afull[18];
    #pragma unroll
    for (int k = 0; k < 9; ++k) {
      f2 a = e2[k] * inv;
      f2 o;
      o[0] = __shfl_xor(a[0], 32, 64);
      o[1] = __shfl_xor(a[1], 32, 64);
      afull[k][0]     = h ? o[0] : a[0];
      afull[k][1]     = h ? o[1] : a[1];
      afull[9 + k][0] = h ? a[0] : o[0];
      afull[9 + k][1] = h ? a[1] : o[1];
    }

    // ---- w2^2 = a^T G a; rows split across halves: h computes rp in [18h, 18h+18) ----
    int iu = __builtin_amdgcn_readfirstlane(i);
    const float* Gi = Gm + (size_t)iu * 1296 + (size_t)h * 18 * 36;
    float w2sq = 0.f;
    #pragma unroll 3
    for (int rp = 0; rp < 18; ++rp) {
      const f2* Gr = (const f2*)(Gi + rp * 36);
      f2 in2 = {0.f, 0.f};
      #pragma unroll
      for (int q = 0; q < 18; ++q) in2 += Gr[q] * afull[q];
      // ar = afull element at global row (h*18 + rp); both indices compile-time
      float ar_lo = (rp & 1) ? afull[rp >> 1][1] : afull[rp >> 1][0];
      float ar_hi = (rp & 1) ? afull[9 + (rp >> 1)][1] : afull[9 + (rp >> 1)][0];
      float ar = h ? ar_hi : ar_lo;
      w2sq = fmaf(ar, in2[0] + in2[1], w2sq);
    }
    w2sq += __shfl_xor(w2sq, 32, 64);              // combine the two half-row partials
    float w2 = __builtin_amdgcn_sqrtf(w2sq);
    float rs6 = 6.f * num * rcpf(fmaxf(w1 * w2, 1e-8f));

    float mw = bmax32(rs6);
    float se = bsum32(__expf(rs6 - mw));
    float sim = (mw + __logf(se)) * (1.f / 6.f);
    if (l == 0) S[i*64 + c] = sim;
  } else {
    // ================= IPOT path (rq/w16 layout, round-18 proven) =================
    int rq = l >> 4, w16 = l & 15;
    int dsel = rq >> 1;
    bool hi = (rq & 1);
    const unsigned* xrow0 = (const unsigned*)(dotb + (size_t)(2048 + c*32 + w16) * 2304 + i*36);
    const unsigned* xrow1 = (const unsigned*)(dotb + (size_t)(2048 + c*32 + w16 + 16) * 2304 + i*36);
    float xnr0 = xnrm[c*32 + w16];
    float xnr1 = xnrm[c*32 + w16 + 16];

    f2 Cm2[9];
    #pragma unroll
    for (int m = 0; m < 9; ++m) {
      unsigned u0 = xrow0[2*m + dsel];
      unsigned u1 = xrow1[2*m + dsel];
      float xv0 = __uint_as_float(hi ? (u0 & 0xFFFF0000u) : (u0 << 16));
      float xv1 = __uint_as_float(hi ? (u1 & 0xFFFF0000u) : (u1 << 16));
      float inr = imnrm[i*36 + 4*m + rq];
      f2 xv;
      xv[0] = xv0 * xnr0;
      xv[1] = xv1 * xnr1;
      Cm2[m] = 1.f - xv * inr;
    }

    f2 Am2[9], Qm2[9];
    float sg[9];
    #pragma unroll
    for (int m = 0; m < 9; ++m) {
      Am2[m][0] = __expf(-2.f * Cm2[m][0]);
      Am2[m][1] = __expf(-2.f * Cm2[m][1]);
      Qm2[m] = Am2[m];
      sg[m] = 1.f / 36.f;
    }
    f2 delta = {0.f, 0.f};
    for (int it = 0; it < 20; ++it) {
      f2 t2 = {0.f, 0.f};
      #pragma unroll
      for (int m = 0; m < 9; ++m) t2 += Qm2[m] * sg[m];
      t2[0] += __shfl_xor(t2[0], 16, 64);
      t2[1] += __shfl_xor(t2[1], 16, 64);
      t2[0] += __shfl_xor(t2[0], 32, 64);
      t2[1] += __shfl_xor(t2[1], 32, 64);
      delta[0] = rcpf(32.f * t2[0]);
      delta[1] = rcpf(32.f * t2[1]);
      #pragma unroll
      for (int m = 0; m < 9; ++m) {
        f2 qd = Qm2[m] * delta;
        float q = bsum16(qd[0] + qd[1]);
        sg[m] = rcpf(36.f * q);
      }
      if (it < 19) {
        #pragma unroll
        for (int m = 0; m < 9; ++m) Qm2[m] = (Am2[m] * delta) * Qm2[m] * sg[m];
      }
    }
    f2 ot2 = {0.f, 0.f};
    #pragma unroll
    for (int m = 0; m < 9; ++m) ot2 += Cm2[m] * (Qm2[m] * delta * sg[m]);
    float ot = bsum16(ot2[0] + ot2[1]);
    ot += __shfl_xor(ot, 16, 64);
    ot += __shfl_xor(ot, 32, 64);
    if (l == 0) Sot[i*64 + c] = -ot;
  }
}

// ---------------- K4: final contrastive reduction ----------------
__global__ __launch_bounds__(256) void k_reduce(const float* __restrict__ Sg,
                                                const float* __restrict__ Sotg,
                                                float* __restrict__ outp) {
  __shared__ float s[4096];
  __shared__ float so[4096];
  __shared__ float red0[256], red1[256];
  int tid = threadIdx.x;
  for (int e = tid; e < 4096; e += 256) { s[e] = Sg[e]; so[e] = Sotg[e]; }
  __syncthreads();
  float m0 = 0.f, m1 = 0.f;
  if (tid < 64) {
    int i = tid;
    float di = s[i*65], dio = so[i*65];
    for (int c2 = 0; c2 < 64; ++c2) {
      if (c2 == i) continue;
      float cs  = fmaxf(0.2f + s[i*64 + c2]  - di,  0.f);
      float cso = fmaxf(0.2f + so[i*64 + c2] - dio, 0.f);
      m0 = fmaxf(m0, cs + 0.1f * cso);
      m1 = fmaxf(m1, cso);
    }
  } else if (tid < 128) {
    int c2 = tid - 64;
    float dc = s[c2*65], dco = so[c2*65];
    for (int i = 0; i < 64; ++i) {
      if (i == c2) continue;
      float cim  = fmaxf(0.2f + s[i*64 + c2]  - dc,  0.f);
      float cimo = fmaxf(0.2f + so[i*64 + c2] - dco, 0.f);
      m0 = fmaxf(m0, cim + 0.1f * cimo);
      m1 = fmaxf(m1, cimo);
    }
  }
  red0[tid] = m0; red1[tid] = m1;
  __syncthreads();
  if (tid == 0) {
    float a0 = 0.f, a1 = 0.f;
    for (int t = 0; t < 128; ++t) { a0 += red0[t]; a1 += red1[t]; }
    outp[0] = a0;
    outp[1] = a1;
  }
}

extern "C" void kernel_launch(void* const* d_in, const int* in_sizes, int n_in,
                              void* d_out, int out_size, void* d_ws, size_t ws_size,
                              hipStream_t stream) {
  (void)in_sizes; (void)n_in; (void)out_size; (void)ws_size;
  const float* im = (const float*)d_in[0];
  const float* s  = (const float*)d_in[1];
  // d_in[2] = s_l (uniform == W, unused)
  const float* x  = (const float*)d_in[3];
  float* out = (float*)d_out;

  unsigned short* Ab   = (unsigned short*)d_ws;              // 4096*1024 bf16
  unsigned short* Bb   = Ab + (size_t)4096 * 1024;           // 2304*1024 bf16
  unsigned short* dotb = Bb + (size_t)2304 * 1024;           // 4096*2304 bf16
  float* G     = (float*)(dotb + (size_t)4096 * 2304);       // 64*36*36
  float* w1    = G + 64*36*36;
  float* xn_r  = w1 + 2048;
  float* imn_r = xn_r + 2048;
  float* S     = imn_r + 2304;
  float* Sot   = S + 4096;

  k_prep<<<dim3(8704), 256, 0, stream>>>(s, x, im, Ab, Bb, w1, xn_r, imn_r, G);
  k_gemm_mfma<<<dim3(24, 32), 256, 0, stream>>>(Ab, Bb, dotb);
  k_pair2<<<dim3(2048), 256, 0, stream>>>(dotb, G, w1, xn_r, imn_r, S, Sot);
  k_reduce<<<dim3(1), 256, 0, stream>>>(S, Sot, out);
}

// Round 20
// 101.567 us; speedup vs baseline: 1.0894x; 1.0894x over previous
//
#include <hip/hip_runtime.h>
#include <cstdint>
#include <cstddef>

// Problem constants: B=64, R=36, W=32, D=1024
// Ab = [s;x] bf16 : 4096 x 1024 (rows 0..2047 = s words, 2048..4095 = x words)
// Bb = im bf16    : 2304 x 1024
// dot bf16        : 4096 x 2304

typedef __attribute__((ext_vector_type(8))) short short8;
typedef __attribute__((ext_vector_type(4))) float f32x4;
typedef __attribute__((ext_vector_type(2))) float f2;   // -> v_pk_* f32 ops

__device__ __forceinline__ unsigned short f2bf(float f) {
  unsigned u = __float_as_uint(f);
  u += 0x7FFFu + ((u >> 16) & 1u);
  return (unsigned short)(u >> 16);
}
__device__ __forceinline__ float rcpf(float x) { return __builtin_amdgcn_rcpf(x); }

// ---------------- K1: fused gram (blocks 0..2303) + prep (blocks 2304..8703) ----------------
__global__ __launch_bounds__(256) void k_prep(const float* __restrict__ s,
                                              const float* __restrict__ x,
                                              const float* __restrict__ im,
                                              unsigned short* __restrict__ Ab,
                                              unsigned short* __restrict__ Bb,
                                              float* __restrict__ w1,
                                              float* __restrict__ xn_r,
                                              float* __restrict__ imn_r,
                                              float* __restrict__ G) {
  int blk = blockIdx.x;
  if (blk < 2304) {
    // ---- gram: G[b] row r = im[b,r,:] @ im[b,:,:]^T (fp32, proven) ----
    int b = blk / 36, r = blk - b * 36;
    int wid = threadIdx.x >> 6, l = threadIdx.x & 63;
    const float* rowr = im + ((size_t)b*36 + r) * 1024;
    float4 my[4];
    #pragma unroll
    for (int j = 0; j < 4; ++j) my[j] = ((const float4*)rowr)[j*64 + l];
    float* Gr = G + ((size_t)b*36 + r) * 36;
    for (int rp = wid; rp < 36; rp += 4) {
      const float* rowp = im + ((size_t)b*36 + rp) * 1024;
      float p = 0.f;
      #pragma unroll
      for (int j = 0; j < 4; ++j) {
        float4 u = ((const float4*)rowp)[j*64 + l];
        p += my[j].x*u.x + my[j].y*u.y + my[j].z*u.z + my[j].w*u.w;
      }
      #pragma unroll
      for (int o = 32; o > 0; o >>= 1) p += __shfl_down(p, o, 64);
      if (l == 0) Gr[rp] = p;
    }
    return;
  }
  // ---- prep: fp32 -> bf16 + norms ----
  int row = blk - 2304, tid = threadIdx.x;
  const float* src; unsigned short* dst; float* np; int recip;
  if (row < 2048)      { src = s  + (size_t)row * 1024;          dst = Ab + (size_t)row * 1024;          np = w1    + row;          recip = 0; }
  else if (row < 4096) { src = x  + (size_t)(row - 2048) * 1024; dst = Ab + (size_t)row * 1024;          np = xn_r  + (row - 2048); recip = 1; }
  else                 { src = im + (size_t)(row - 4096) * 1024; dst = Bb + (size_t)(row - 4096) * 1024; np = imn_r + (row - 4096); recip = 1; }
  float4 f = ((const float4*)src)[tid];
  ushort4 h;
  h.x = f2bf(f.x); h.y = f2bf(f.y); h.z = f2bf(f.z); h.w = f2bf(f.w);
  ((ushort4*)dst)[tid] = h;
  float p = f.x*f.x + f.y*f.y + f.z*f.z + f.w*f.w;
  #pragma unroll
  for (int o = 32; o > 0; o >>= 1) p += __shfl_down(p, o, 64);
  __shared__ float red[4];
  if ((tid & 63) == 0) red[tid >> 6] = p;
  __syncthreads();
  if (tid == 0) {
    float n = sqrtf(red[0] + red[1] + red[2] + red[3]);
    *np = recip ? 1.f / (n + 1e-12f) : n;
  }
}

// ---------------- K2: bf16 MFMA GEMM, 128x96 tile (grid 24x32 = 768 = 3/CU exact) ----------------
__global__ __launch_bounds__(256) void k_gemm_mfma(const unsigned short* __restrict__ A,
                                                   const unsigned short* __restrict__ B,
                                                   unsigned short* __restrict__ dot) {
  __shared__ unsigned short lA[128 * 32];
  __shared__ unsigned short lB[96 * 32];
  int tid = threadIdx.x;
  int bn = blockIdx.x * 96, bm = blockIdx.y * 128;
  int wid = tid >> 6, l = tid & 63;
  int wr = (wid >> 1) * 64, wc = (wid & 1) * 48;
  int lr = l & 15, lq = l >> 4;

  f32x4 acc[4][3] = {};

  int row_a = tid >> 2;
  int kq = (tid & 3) * 8;
  const unsigned short* gA = A + (size_t)(bm + row_a) * 1024 + kq;
  const unsigned short* gB = B + (size_t)(bn + row_a) * 1024 + kq;    // rows 0..63
  unsigned loff = (unsigned)tid * 16u;

  for (int kt = 0; kt < 1024; kt += 32) {
    __builtin_amdgcn_global_load_lds(
        (const __attribute__((address_space(1))) void*)(gA + kt),
        (__attribute__((address_space(3))) void*)((char*)lA + loff), 16, 0, 0);
    __builtin_amdgcn_global_load_lds(
        (const __attribute__((address_space(1))) void*)(gA + 64*1024 + kt),
        (__attribute__((address_space(3))) void*)((char*)lA + 4096 + loff), 16, 0, 0);
    __builtin_amdgcn_global_load_lds(
        (const __attribute__((address_space(1))) void*)(gB + kt),
        (__attribute__((address_space(3))) void*)((char*)lB + loff), 16, 0, 0);
    if (tid < 128)                                                     // rows 64..95
      __builtin_amdgcn_global_load_lds(
          (const __attribute__((address_space(1))) void*)(gB + 64*1024 + kt),
          (__attribute__((address_space(3))) void*)((char*)lB + 4096 + loff), 16, 0, 0);
    __syncthreads();

    short8 af[4], bfr[3];
    #pragma unroll
    for (int mi = 0; mi < 4; ++mi)
      af[mi] = *(const short8*)&lA[(wr + mi*16 + lr) * 32 + lq * 8];
    #pragma unroll
    for (int ni = 0; ni < 3; ++ni)
      bfr[ni] = *(const short8*)&lB[(wc + ni*16 + lr) * 32 + lq * 8];
    #pragma unroll
    for (int mi = 0; mi < 4; ++mi)
      #pragma unroll
      for (int ni = 0; ni < 3; ++ni)
        acc[mi][ni] = __builtin_amdgcn_mfma_f32_16x16x32_bf16(af[mi], bfr[ni], acc[mi][ni], 0, 0, 0);
    __syncthreads();
  }

  // C/D layout: col = lane&15, row = (lane>>4)*4 + reg
  #pragma unroll
  for (int mi = 0; mi < 4; ++mi)
    #pragma unroll
    for (int ni = 0; ni < 3; ++ni) {
      int gcol = bn + wc + ni*16 + lr;
      #pragma unroll
      for (int q = 0; q < 4; ++q) {
        int grow = bm + wr + mi*16 + lq*4 + q;
        dot[(size_t)grow * 2304 + gcol] = f2bf(acc[mi][ni][q]);
      }
    }
}

// ---------------- wave reduction helpers ----------------
template<int C>
__device__ __forceinline__ float dpp_add(float v) {
  return v + __int_as_float(__builtin_amdgcn_mov_dpp(__float_as_int(v), C, 0xF, 0xF, true));
}
template<int C>
__device__ __forceinline__ float dpp_max(float v) {
  return fmaxf(v, __int_as_float(__builtin_amdgcn_mov_dpp(__float_as_int(v), C, 0xF, 0xF, true)));
}
__device__ __forceinline__ float bsum32(float v) {   // sum over lane bits 0..4
  v = dpp_add<0xB1>(v);    // xor1
  v = dpp_add<0x4E>(v);    // xor2
  v = dpp_add<0x141>(v);   // half mirror (xor4-equiv)
  v = dpp_add<0x128>(v);   // row_ror:8 (xor8-equiv)
  v += __shfl_xor(v, 16, 64);
  return v;
}
__device__ __forceinline__ float bsum16(float v) {   // sum over lane bits 0..3 (one DPP row), all-VALU
  v = dpp_add<0xB1>(v);
  v = dpp_add<0x4E>(v);
  v = dpp_add<0x141>(v);
  v = dpp_add<0x128>(v);
  return v;
}
__device__ __forceinline__ float bmax32(float v) {
  v = dpp_max<0xB1>(v);
  v = dpp_max<0x4E>(v);
  v = dpp_max<0x141>(v);
  v = dpp_max<0x128>(v);
  v = fmaxf(v, __shfl_xor(v, 16, 64));
  return v;
}

// ---------------- K3: wave-role split — even waves = score (proven layout),
//                      odd waves = IPOT (rq/w16 layout: DPP-only w-sums, 9 rcp/iter) ----------------
__global__ __launch_bounds__(256, 4) void k_pair2(const unsigned short* __restrict__ dotb,
                                                  const float* __restrict__ Gm,
                                                  const float* __restrict__ w1m,
                                                  const float* __restrict__ xnrm,
                                                  const float* __restrict__ imnrm,
                                                  float* __restrict__ S,
                                                  float* __restrict__ Sot) {
  int wid  = threadIdx.x >> 6;
  int g    = blockIdx.x * 4 + wid;           // 0..8191
  int pair = g >> 1;                         // 0..4095
  int role = g & 1;                          // 0 = score, 1 = ipot
  int c = pair >> 6, i = pair & 63;
  int l = threadIdx.x & 63;

  if (role == 0) {
    // ================= SCORE path (proven layout: h = l>>5, w = l&31) =================
    int h = l >> 5, w = l & 31;
    int r0 = h * 18;
    const unsigned* drow = (const unsigned*)(dotb + (size_t)(c*32 + w) * 2304 + i*36 + r0);
    float w1 = w1m[c*32 + w];

    f2 d2[9];
    #pragma unroll
    for (int k = 0; k < 9; ++k) {
      unsigned u = drow[k];
      d2[k][0] = __uint_as_float(u << 16);
      d2[k][1] = __uint_as_float(u & 0xFFFF0000u);
    }

    f2 p2[9];
    #pragma unroll
    for (int k = 0; k < 9; ++k) {
      f2 t = d2[k] * 0.1f;
      f2 fv;
      fv[0] = fmaxf(d2[k][0], t[0]);
      fv[1] = fmaxf(d2[k][1], t[1]);
      f2 sq = fv * fv;
      float t0 = bsum32(sq[0]);
      float t1 = bsum32(sq[1]);
      f2 rs;   // 9/sqrt(t) = rsqrt(t/81)
      rs[0] = __builtin_amdgcn_rsqf(fmaxf(t0 * 0.012345679f, 1e-30f));
      rs[1] = __builtin_amdgcn_rsqf(fmaxf(t1 * 0.012345679f, 1e-30f));
      p2[k] = fv * rs;
    }
    float mx = fmaxf(fmaxf(p2[0][0], p2[0][1]), fmaxf(p2[1][0], p2[1][1]));
    #pragma unroll
    for (int k = 2; k < 9; ++k) mx = fmaxf(mx, fmaxf(p2[k][0], p2[k][1]));
    mx = fmaxf(mx, __shfl_xor(mx, 32, 64));        // max over all 36 r

    f2 e2[9];
    f2 sum2 = {0.f, 0.f}, nu2 = {0.f, 0.f};
    #pragma unroll
    for (int k = 0; k < 9; ++k) {
      e2[k][0] = __expf(p2[k][0] - mx);
      e2[k][1] = __expf(p2[k][1] - mx);
      sum2 += e2[k];
      nu2 += e2[k] * d2[k];
    }
    float sum = sum2[0] + sum2[1];
    float numu = nu2[0] + nu2[1];
    sum  += __shfl_xor(sum, 32, 64);
    numu += __shfl_xor(numu, 32, 64);
    float inv = rcpf(sum);
    float num = numu * inv;

    f2 afull[18];
    #pragma unroll
    for (int k = 0; k < 9; ++k) {
      f2 a = e2[k] * inv;
      f2 o;
      o[0] = __shfl_xor(a[0], 32, 64);
      o[1] = __shfl_xor(a[1], 32, 64);
      afull[k][0]     = h ? o[0] : a[0];
      afull[k][1]     = h ? o[1] : a[1];
      afull[9 + k][0] = h ? a[0] : o[0];
      afull[9 + k][1] = h ? a[1] : o[1];
    }

    // ---- w2^2 = a^T G a; G rows wave-uniform -> scalar loads (keep ALL rows per lane) ----
    int iu = __builtin_amdgcn_readfirstlane(i);
    const float* Gi = Gm + (size_t)iu * 1296;
    float w2sq = 0.f;
    #pragma unroll 4
    for (int rp = 0; rp < 36; ++rp) {
      const f2* Gr = (const f2*)(Gi + rp * 36);
      f2 in2 = {0.f, 0.f};
      #pragma unroll
      for (int q = 0; q < 18; ++q) in2 += Gr[q] * afull[q];
      float ar = (rp & 1) ? afull[rp >> 1][1] : afull[rp >> 1][0];
      w2sq = fmaf(ar, in2[0] + in2[1], w2sq);
    }
    float w2 = __builtin_amdgcn_sqrtf(w2sq);
    float rs6 = 6.f * num * rcpf(fmaxf(w1 * w2, 1e-8f));

    float mw = bmax32(rs6);
    float se = bsum32(__expf(rs6 - mw));
    float sim = (mw + __logf(se)) * (1.f / 6.f);
    if (l == 0) S[i*64 + c] = sim;
  } else {
    // ================= IPOT path (rq/w16 layout, round-18 proven) =================
    int rq = l >> 4, w16 = l & 15;
    int dsel = rq >> 1;
    bool hi = (rq & 1);
    const unsigned* xrow0 = (const unsigned*)(dotb + (size_t)(2048 + c*32 + w16) * 2304 + i*36);
    const unsigned* xrow1 = (const unsigned*)(dotb + (size_t)(2048 + c*32 + w16 + 16) * 2304 + i*36);
    float xnr0 = xnrm[c*32 + w16];
    float xnr1 = xnrm[c*32 + w16 + 16];

    f2 Cm2[9];
    #pragma unroll
    for (int m = 0; m < 9; ++m) {
      unsigned u0 = xrow0[2*m + dsel];
      unsigned u1 = xrow1[2*m + dsel];
      float xv0 = __uint_as_float(hi ? (u0 & 0xFFFF0000u) : (u0 << 16));
      float xv1 = __uint_as_float(hi ? (u1 & 0xFFFF0000u) : (u1 << 16));
      float inr = imnrm[i*36 + 4*m + rq];
      f2 xv;
      xv[0] = xv0 * xnr0;
      xv[1] = xv1 * xnr1;
      Cm2[m] = 1.f - xv * inr;
    }

    f2 Am2[9], Qm2[9];
    float sg[9];
    #pragma unroll
    for (int m = 0; m < 9; ++m) {
      Am2[m][0] = __expf(-2.f * Cm2[m][0]);
      Am2[m][1] = __expf(-2.f * Cm2[m][1]);
      Qm2[m] = Am2[m];
      sg[m] = 1.f / 36.f;
    }
    f2 delta = {0.f, 0.f};
    for (int it = 0; it < 20; ++it) {
      f2 t2 = {0.f, 0.f};
      #pragma unroll
      for (int m = 0; m < 9; ++m) t2 += Qm2[m] * sg[m];
      t2[0] += __shfl_xor(t2[0], 16, 64);
      t2[1] += __shfl_xor(t2[1], 16, 64);
      t2[0] += __shfl_xor(t2[0], 32, 64);
      t2[1] += __shfl_xor(t2[1], 32, 64);
      delta[0] = rcpf(32.f * t2[0]);
      delta[1] = rcpf(32.f * t2[1]);
      #pragma unroll
      for (int m = 0; m < 9; ++m) {
        f2 qd = Qm2[m] * delta;
        float q = bsum16(qd[0] + qd[1]);
        sg[m] = rcpf(36.f * q);
      }
      if (it < 19) {
        #pragma unroll
        for (int m = 0; m < 9; ++m) Qm2[m] = (Am2[m] * delta) * Qm2[m] * sg[m];
      }
    }
    f2 ot2 = {0.f, 0.f};
    #pragma unroll
    for (int m = 0; m < 9; ++m) ot2 += Cm2[m] * (Qm2[m] * delta * sg[m]);
    float ot = bsum16(ot2[0] + ot2[1]);
    ot += __shfl_xor(ot, 16, 64);
    ot += __shfl_xor(ot, 32, 64);
    if (l == 0) Sot[i*64 + c] = -ot;
  }
}

// ---------------- K4: final contrastive reduction ----------------
__global__ __launch_bounds__(256) void k_reduce(const float* __restrict__ Sg,
                                                const float* __restrict__ Sotg,
                                                float* __restrict__ outp) {
  __shared__ float s[4096];
  __shared__ float so[4096];
  __shared__ float red0[256], red1[256];
  int tid = threadIdx.x;
  for (int e = tid; e < 4096; e += 256) { s[e] = Sg[e]; so[e] = Sotg[e]; }
  __syncthreads();
  float m0 = 0.f, m1 = 0.f;
  if (tid < 64) {
    int i = tid;
    float di = s[i*65], dio = so[i*65];
    for (int c2 = 0; c2 < 64; ++c2) {
      if (c2 == i) continue;
      float cs  = fmaxf(0.2f + s[i*64 + c2]  - di,  0.f);
      float cso = fmaxf(0.2f + so[i*64 + c2] - dio, 0.f);
      m0 = fmaxf(m0, cs + 0.1f * cso);
      m1 = fmaxf(m1, cso);
    }
  } else if (tid < 128) {
    int c2 = tid - 64;
    float dc = s[c2*65], dco = so[c2*65];
    for (int i = 0; i < 64; ++i) {
      if (i == c2) continue;
      float cim  = fmaxf(0.2f + s[i*64 + c2]  - dc,  0.f);
      float cimo = fmaxf(0.2f + so[i*64 + c2] - dco, 0.f);
      m0 = fmaxf(m0, cim + 0.1f * cimo);
      m1 = fmaxf(m1, cimo);
    }
  }
  red0[tid] = m0; red1[tid] = m1;
  __syncthreads();
  if (tid == 0) {
    float a0 = 0.f, a1 = 0.f;
    for (int t = 0; t < 128; ++t) { a0 += red0[t]; a1 += red1[t]; }
    outp[0] = a0;
    outp[1] = a1;
  }
}

extern "C" void kernel_launch(void* const* d_in, const int* in_sizes, int n_in,
                              void* d_out, int out_size, void* d_ws, size_t ws_size,
                              hipStream_t stream) {
  (void)in_sizes; (void)n_in; (void)out_size; (void)ws_size;
  const float* im = (const float*)d_in[0];
  const float* s  = (const float*)d_in[1];
  // d_in[2] = s_l (uniform == W, unused)
  const float* x  = (const float*)d_in[3];
  float* out = (float*)d_out;

  unsigned short* Ab   = (unsigned short*)d_ws;              // 4096*1024 bf16
  unsigned short* Bb   = Ab + (size_t)4096 * 1024;           // 2304*1024 bf16
  unsigned short* dotb = Bb + (size_t)2304 * 1024;           // 4096*2304 bf16
  float* G     = (float*)(dotb + (size_t)4096 * 2304);       // 64*36*36
  float* w1    = G + 64*36*36;
  float* xn_r  = w1 + 2048;
  float* imn_r = xn_r + 2048;
  float* S     = imn_r + 2304;
  float* Sot   = S + 4096;

  k_prep<<<dim3(8704), 256, 0, stream>>>(s, x, im, Ab, Bb, w1, xn_r, imn_r, G);
  k_gemm_mfma<<<dim3(24, 32), 256, 0, stream>>>(Ab, Bb, dotb);
  k_pair2<<<dim3(2048), 256, 0, stream>>>(dotb, G, w1, xn_r, imn_r, S, Sot);
  k_reduce<<<dim3(1), 256, 0, stream>>>(S, Sot, out);
}